// Round 8
// baseline (472.492 us; speedup 1.0000x reference)
//
#include <hip/hip_runtime.h>
#include <hip/hip_bf16.h>

#define MD 8192
#define KD 4096
#define ND 4096

typedef __bf16 bf16x8 __attribute__((ext_vector_type(8)));
typedef float f32x4 __attribute__((ext_vector_type(4)));

__device__ __forceinline__ float gelu_ss(float v) {
    float t = 0.7978845608f * fmaf(0.044715f * v * v, v, v);
    float r = t * __builtin_amdgcn_rcpf(1.0f + fabsf(t));
    return 0.5f * v * (1.0f + r);
}

// ---------------------------------------------------------------------------
// x: fp32 -> bf16, row-major (A staging reads rows)
// ---------------------------------------------------------------------------
__global__ void cvt_bf16(const float* __restrict__ in, __bf16* __restrict__ out, int n8) {
    int i = blockIdx.x * 256 + threadIdx.x;
    int stride = gridDim.x * 256;
    for (; i < n8; i += stride) {
        const float4* p = (const float4*)(in + (size_t)i * 8);
        float4 a = p[0], b = p[1];
        bf16x8 v;
        v[0]=(__bf16)a.x; v[1]=(__bf16)a.y; v[2]=(__bf16)a.z; v[3]=(__bf16)a.w;
        v[4]=(__bf16)b.x; v[5]=(__bf16)b.y; v[6]=(__bf16)b.z; v[7]=(__bf16)b.w;
        *(bf16x8*)(out + (size_t)i * 8) = v;
    }
}

// ---------------------------------------------------------------------------
// W: fp32 [N][K] -> B' fragment layout [colblk=N/16][kblk=K/32][64 lanes x 16B]
// lane (lr=lane&15, kg=lane>>4) holds W[colblk*16+lr][kblk*32+kg*8 .. +8] as bf16
// -> main kernel's B-frag load = one coalesced 1KB global_load_dwordx4/wave.
// ---------------------------------------------------------------------------
__global__ void cvt_wfrag(const float* __restrict__ W, __bf16* __restrict__ out) {
    unsigned wave = (blockIdx.x * 256u + threadIdx.x) >> 6;   // 0..32767
    unsigned lane = threadIdx.x & 63u;
    unsigned cb = wave >> 7;          // colblk 0..255  (N/16)
    unsigned kb = wave & 127u;        // kblk   0..127  (K/32)
    unsigned lr = lane & 15u, kg = lane >> 4;
    const float* src = W + (size_t)(cb * 16u + lr) * KD + kb * 32u + kg * 8u;
    float4 a = *(const float4*)src;
    float4 b = *(const float4*)(src + 4);
    bf16x8 v;
    v[0]=(__bf16)a.x; v[1]=(__bf16)a.y; v[2]=(__bf16)a.z; v[3]=(__bf16)a.w;
    v[4]=(__bf16)b.x; v[5]=(__bf16)b.y; v[6]=(__bf16)b.z; v[7]=(__bf16)b.w;
    *(bf16x8*)(out + ((size_t)cb * 128u + kb) * 512u + lane * 8u) = v;
}

// ---------------------------------------------------------------------------
// GEMM+epilogue: 256x256, BK=64. A via LDS (2 bufs, 64 KiB, global_load_lds,
// both-sides swizzle); B DIRECT global->VGPR from B' (coalesced, dbuf regs,
// counted vmcnt across the single per-tile barrier).
// ---------------------------------------------------------------------------
#define BMg 256
#define BNg 256
#define BKg 64
#define KTg (KD / BKg)   // 64

__device__ __forceinline__ void gload_lds16(const void* g, void* l) {
    __builtin_amdgcn_global_load_lds(
        (const __attribute__((address_space(1))) void*)g,
        (__attribute__((address_space(3))) void*)l, 16, 0, 0);
}

__global__ __launch_bounds__(512, 1) void gemm_bf16_lse(
    const __bf16* __restrict__ xb, const __bf16* __restrict__ Wfr,
    const float* __restrict__ bias, float* __restrict__ rowsum)
{
    // A only: [buf][256*64 bf16] = 2 x 32 KiB = 64 KiB
    __shared__ alignas(16) __bf16 lds[2][BMg * BKg];

    const unsigned nblk = (MD / BMg) * (ND / BNg);   // 512
    unsigned bid  = blockIdx.x;
    unsigned sbid = (bid & 7u) * (nblk / 8u) + (bid >> 3);
    unsigned bm = sbid / (ND / BNg);
    unsigned bn = sbid % (ND / BNg);

    const unsigned tid  = threadIdx.x;
    const unsigned lane = tid & 63u;
    const unsigned wid  = tid >> 6;      // 0..7
    const unsigned wr   = wid >> 2;      // 0..1 -> 128 rows
    const unsigned wc   = wid & 3u;      // 0..3 -> 64 cols
    const unsigned lr   = lane & 15u;
    const unsigned kg   = lane >> 4;
    const unsigned x7   = lr & 7u;

    // --- A staging: chunk ch -> row = ch>>3, slot = ch&7; LDS linear (DMA),
    // global col-slot pre-swizzled cg = slot ^ (row&7)  (rule #21).
    unsigned ch0 = tid, ch1 = tid + 512u;
    unsigned sr0 = ch0 >> 3, cg0 = (ch0 & 7u) ^ (sr0 & 7u);
    unsigned sr1 = ch1 >> 3, cg1 = (ch1 & 7u) ^ (sr1 & 7u);
    const __bf16* gA0 = xb + (size_t)(bm * BMg + sr0) * KD + cg0 * 8u;
    const __bf16* gA1 = xb + (size_t)(bm * BMg + sr1) * KD + cg1 * 8u;

    // --- B' direct-load base: colblk = bn*16 + wc*4 (+nf), kblk = t*2 (+ks)
    const char* gBp = (const char*)Wfr
        + (size_t)(bn * 16u + wc * 4u) * 128u * 1024u + lane * 16u;

    f32x4 acc[8][4] = {};
    bf16x8 bB0[4][2], bB1[4][2];   // [nf][ks], two static sets (rule #20)

    auto stA = [&](unsigned bsel, int t) {
        size_t off = (size_t)t * 64u;
        gload_lds16(gA0 + off,               &lds[bsel][(ch0) * 8u]);
        gload_lds16(gA1 + off,               &lds[bsel][(ch1) * 8u]);
        gload_lds16(gA0 + 128u * KD + off,   &lds[bsel][(1024u + ch0) * 8u]);
        gload_lds16(gA1 + 128u * KD + off,   &lds[bsel][(1024u + ch1) * 8u]);
    };
    auto loadB = [&](bf16x8 (*dst)[2], int t) {
        #pragma unroll
        for (int nf = 0; nf < 4; ++nf)
            #pragma unroll
            for (int ks = 0; ks < 2; ++ks)
                dst[nf][ks] = *(const bf16x8*)(
                    gBp + ((size_t)nf * 128u + (unsigned)(t * 2 + ks)) * 1024u);
    };
    auto loadAq = [&](unsigned bsel, unsigned mh, unsigned ks, bf16x8* dst) {
        const char* As = (const char*)&lds[bsel][0];
        #pragma unroll
        for (int a = 0; a < 4; ++a) {
            unsigned ro = (wr * 128u + (mh * 4u + a) * 16u + lr) * 128u;
            dst[a] = *(const bf16x8*)(As + ro + ((ks * 4u + kg) ^ x7) * 16u);
        }
    };
    auto mfmaQ = [&](unsigned mh, const bf16x8* a4, bf16x8 (*bset)[2], unsigned ks) {
        __builtin_amdgcn_s_setprio(1);
        #pragma unroll
        for (int a = 0; a < 4; ++a)
            #pragma unroll
            for (int nf = 0; nf < 4; ++nf)
                acc[mh * 4 + a][nf] = __builtin_amdgcn_mfma_f32_16x16x32_bf16(
                    a4[a], bset[nf][ks], acc[mh * 4 + a][nf], 0, 0, 0);
        __builtin_amdgcn_s_setprio(0);
    };

    auto body = [&](unsigned cb, int t, bf16x8 (*bcur)[2], bf16x8 (*bnxt)[2]) {
        __builtin_amdgcn_sched_barrier(0);
        bf16x8 aP[4], aQ[4];
        loadAq(cb, 0, 0, aP);                     // ds c0 (mh0,ks0)
        loadAq(cb, 1, 0, aQ);                     // ds c1 (mh1,ks0)
        if (t + 1 < KTg) {
            stA(cb ^ 1u, t + 1);                  // 4 gload_lds
            loadB(bnxt, t + 1);                   // 8 coalesced dwordx4
            asm volatile("s_waitcnt vmcnt(12)" ::: "memory");  // B(t) certified
        } else {
            asm volatile("s_waitcnt vmcnt(0)" ::: "memory");
        }
        __builtin_amdgcn_sched_barrier(0);        // loads stay above MFMA
        mfmaQ(0, aP, bcur, 0);
        loadAq(cb, 0, 1, aP);                     // ds c2 (mh0,ks1)
        mfmaQ(1, aQ, bcur, 0);
        loadAq(cb, 1, 1, aQ);                     // ds c3 (mh1,ks1)
        mfmaQ(0, aP, bcur, 1);
        mfmaQ(1, aQ, bcur, 1);
        if (t + 1 < KTg) {
            asm volatile("s_waitcnt vmcnt(8)" ::: "memory");   // A(t+1) landed
        }
        __builtin_amdgcn_sched_barrier(0);
        __builtin_amdgcn_s_barrier();             // B(t+1) stays in flight (T4)
    };

    // prologue: A(0)->buf0, B(0)->bB0; certify A(0)
    stA(0, 0);
    loadB(bB0, 0);
    asm volatile("s_waitcnt vmcnt(8)" ::: "memory");
    __builtin_amdgcn_s_barrier();

    for (int t = 0; t < KTg; t += 2) {
        body(0u, t,     bB0, bB1);
        body(1u, t + 1, bB1, bB0);
    }

    // ---- epilogue: bias + leaky^2 + gelu^2 + exp + row partial sums ----
    // C/D layout: col = lane&15 (=lr), row = kg*4 + j
    unsigned row_base = bm * BMg + wr * 128u;
    unsigned col_base = bn * BNg + wc * 64u;
    float bb[4];
    #pragma unroll
    for (int nf = 0; nf < 4; ++nf) bb[nf] = bias[col_base + nf * 16u + lr];
    #pragma unroll
    for (int mf = 0; mf < 8; ++mf) {
        float s[4] = {0.f, 0.f, 0.f, 0.f};
        #pragma unroll
        for (int nf = 0; nf < 4; ++nf) {
            #pragma unroll
            for (int j = 0; j < 4; ++j) {
                float v = acc[mf][nf][j] + bb[nf];
                v = v > 0.0f ? v : 1e-4f * v;      // two leaky-relus fused
                v = gelu_ss(gelu_ss(v));
                s[j] += __expf(v);
            }
        }
        #pragma unroll
        for (int j = 0; j < 4; ++j) {
            float t = s[j];
            t += __shfl_xor(t, 1);
            t += __shfl_xor(t, 2);
            t += __shfl_xor(t, 4);
            t += __shfl_xor(t, 8);
            if (lr == 0)
                atomicAdd(&rowsum[row_base + mf * 16u + kg * 4u + j], t);
        }
    }
}

// ---------------------------------------------------------------------------
// Fallback (round-2 kernel): fused fp32 staging, used only if ws too small.
// ---------------------------------------------------------------------------
#define BM 256
#define BN 256
#define BK 64
#define NBLK ((MD / BM) * (ND / BN))

__device__ __forceinline__ unsigned swz(unsigned row, unsigned kbyte) {
    return row * (BK * 2u) + (kbyte ^ ((row & 7u) << 4));
}

__global__ __launch_bounds__(512, 1) void fused_gemm_lse(
    const float* __restrict__ x, const float* __restrict__ W,
    const float* __restrict__ bias, float* __restrict__ rowsum)
{
    __shared__ alignas(16) __bf16 lds[2][2][BM * BK];
    unsigned bid  = blockIdx.x;
    unsigned sbid = (bid & 7u) * (NBLK / 8u) + (bid >> 3);
    unsigned bm = sbid / (ND / BN);
    unsigned bn = sbid % (ND / BN);
    const unsigned tid  = threadIdx.x;
    const unsigned lane = tid & 63u;
    const unsigned wid  = tid >> 6;
    const unsigned wr   = wid >> 2;
    const unsigned wc   = wid & 3u;
    const unsigned lr   = lane & 15u;
    const unsigned kg   = lane >> 4;
    const float* gA = x + (size_t)bm * BM * KD;
    const float* gB = W + (size_t)bn * BN * KD;
    const unsigned s_row = tid >> 3;
    const unsigned s_c8  = tid & 7u;
    f32x4 acc[8][4] = {};
    float4 ra[8], rb[8];
    auto issue = [&](const float* g, int kt, float4* r) {
        #pragma unroll
        for (int i = 0; i < 4; ++i) {
            unsigned row = s_row + 64u * i;
            size_t goff = (size_t)row * KD + (size_t)kt * BK + (size_t)s_c8 * 8u;
            r[i * 2]     = *(const float4*)(g + goff);
            r[i * 2 + 1] = *(const float4*)(g + goff + 4);
        }
    };
    auto writeT = [&](char* dst, const float4* r) {
        #pragma unroll
        for (int i = 0; i < 4; ++i) {
            unsigned row = s_row + 64u * i;
            float4 lo = r[i * 2], hi = r[i * 2 + 1];
            bf16x8 v;
            v[0]=(__bf16)lo.x; v[1]=(__bf16)lo.y; v[2]=(__bf16)lo.z; v[3]=(__bf16)lo.w;
            v[4]=(__bf16)hi.x; v[5]=(__bf16)hi.y; v[6]=(__bf16)hi.z; v[7]=(__bf16)hi.w;
            *(bf16x8*)(dst + swz(row, s_c8 * 16u)) = v;
        }
    };
    auto compute = [&](int cur) {
        const char* AsB = (const char*)&lds[cur][0][0];
        const char* BsB = (const char*)&lds[cur][1][0];
        #pragma unroll
        for (int ks = 0; ks < 2; ++ks) {
            unsigned kb = (unsigned)ks * 64u + kg * 16u;
            bf16x8 bfr[4];
            #pragma unroll
            for (int ni = 0; ni < 4; ++ni)
                bfr[ni] = *(const bf16x8*)(BsB + swz(wc * 64u + ni * 16u + lr, kb));
            #pragma unroll
            for (int mh = 0; mh < 2; ++mh) {
                bf16x8 af[4];
                #pragma unroll
                for (int a = 0; a < 4; ++a)
                    af[a] = *(const bf16x8*)(AsB + swz(wr * 128u + mh * 64u + a * 16u + lr, kb));
                __builtin_amdgcn_s_setprio(1);
                #pragma unroll
                for (int a = 0; a < 4; ++a)
                    #pragma unroll
                    for (int ni = 0; ni < 4; ++ni)
                        acc[mh * 4 + a][ni] = __builtin_amdgcn_mfma_f32_16x16x32_bf16(
                            af[a], bfr[ni], acc[mh * 4 + a][ni], 0, 0, 0);
                __builtin_amdgcn_s_setprio(0);
            }
        }
    };
    issue(gA, 0, ra); issue(gB, 0, rb);
    writeT((char*)&lds[0][0][0], ra);
    writeT((char*)&lds[0][1][0], rb);
    __syncthreads();
    int cur = 0;
    for (int kt = 0; kt < KD / BK - 1; ++kt) {
        issue(gA, kt + 1, ra);
        issue(gB, kt + 1, rb);
        compute(cur);
        writeT((char*)&lds[cur ^ 1][0][0], ra);
        writeT((char*)&lds[cur ^ 1][1][0], rb);
        __syncthreads();
        cur ^= 1;
    }
    compute(cur);
    unsigned row_base = bm * BM + wr * 128u;
    unsigned col_base = bn * BN + wc * 64u;
    float bb[4];
    #pragma unroll
    for (int ni = 0; ni < 4; ++ni) bb[ni] = bias[col_base + ni * 16u + lr];
    #pragma unroll
    for (int mi = 0; mi < 8; ++mi) {
        float s[4] = {0.f, 0.f, 0.f, 0.f};
        #pragma unroll
        for (int ni = 0; ni < 4; ++ni) {
            #pragma unroll
            for (int j = 0; j < 4; ++j) {
                float v = acc[mi][ni][j] + bb[ni];
                v = v > 0.0f ? v : 1e-4f * v;
                v = gelu_ss(gelu_ss(v));
                s[j] += __expf(v);
            }
        }
        #pragma unroll
        for (int j = 0; j < 4; ++j) {
            float t = s[j];
            t += __shfl_xor(t, 1);
            t += __shfl_xor(t, 2);
            t += __shfl_xor(t, 4);
            t += __shfl_xor(t, 8);
            if (lr == 0)
                atomicAdd(&rowsum[row_base + mi * 16u + kg * 4u + j], t);
        }
    }
}

__global__ void lse_log(float* __restrict__ out) {
    int i = blockIdx.x * 256 + threadIdx.x;
    if (i < MD) out[i] = logf(out[i]);
}

extern "C" void kernel_launch(void* const* d_in, const int* in_sizes, int n_in,
                              void* d_out, int out_size, void* d_ws, size_t ws_size,
                              hipStream_t stream) {
    (void)in_sizes; (void)n_in; (void)out_size;
    const float* x = (const float*)d_in[0];
    const float* W = (const float*)d_in[1];
    const float* b = (const float*)d_in[2];
    float* out = (float*)d_out;

    hipMemsetAsync(out, 0, (size_t)MD * sizeof(float), stream);

    size_t need = ((size_t)MD * KD + (size_t)ND * KD) * sizeof(__bf16);  // 100.7 MB
    if (ws_size >= need) {
        __bf16* xb  = (__bf16*)d_ws;
        __bf16* Wfr = xb + (size_t)MD * KD;
        cvt_bf16<<<2048, 256, 0, stream>>>(x, xb, MD * KD / 8);
        cvt_wfrag<<<(ND / 16) * (KD / 32) / 4, 256, 0, stream>>>(W, Wfr);
        gemm_bf16_lse<<<(MD / BMg) * (ND / BNg), 512, 0, stream>>>(xb, Wfr, b, out);
    } else {
        fused_gemm_lse<<<NBLK, 512, 0, stream>>>(x, W, b, out);
    }
    lse_log<<<MD / 256, 256, 0, stream>>>(out);
}

// Round 9
// 320.405 us; speedup vs baseline: 1.4747x; 1.4747x over previous
//
#include <hip/hip_runtime.h>
#include <hip/hip_bf16.h>

#define MD 8192
#define KD 4096
#define ND 4096

typedef __bf16 bf16x8 __attribute__((ext_vector_type(8)));
typedef float f32x4 __attribute__((ext_vector_type(4)));

__device__ __forceinline__ float gelu_ss(float v) {
    float t = 0.7978845608f * fmaf(0.044715f * v * v, v, v);
    float r = t * __builtin_amdgcn_rcpf(1.0f + fabsf(t));
    return 0.5f * v * (1.0f + r);
}

// ---------------------------------------------------------------------------
// fp32 -> bf16 convert (memory-bound; inputs are L3-resident after 1st replay)
// ---------------------------------------------------------------------------
__global__ void cvt_bf16(const float* __restrict__ in, __bf16* __restrict__ out, int n8) {
    int i = blockIdx.x * 256 + threadIdx.x;
    int stride = gridDim.x * 256;
    for (; i < n8; i += stride) {
        const float4* p = (const float4*)(in + (size_t)i * 8);
        float4 a = p[0], b = p[1];
        bf16x8 v;
        v[0]=(__bf16)a.x; v[1]=(__bf16)a.y; v[2]=(__bf16)a.z; v[3]=(__bf16)a.w;
        v[4]=(__bf16)b.x; v[5]=(__bf16)b.y; v[6]=(__bf16)b.z; v[7]=(__bf16)b.w;
        *(bf16x8*)(out + (size_t)i * 8) = v;
    }
}

// ---------------------------------------------------------------------------
// GEMM+epilogue: 256x256, BK=32, 4 LDS bufs (never-drain, 3-tile lead),
// 2 quadrant-phases per K-tile with the m201 barrier sandwich:
//   {ds_reads, stage-unit, [lgkm hint], BAR, lgkm0, setprio 16xMFMA, BAR}
// vmcnt(8) counted mid-p1 certifies tile t+1 one phase before first use.
// ---------------------------------------------------------------------------
#define BMg 256
#define BNg 256
#define BKg 32
#define KTg (KD / BKg)   // 128

__device__ __forceinline__ void gload_lds16(const void* g, void* l) {
    __builtin_amdgcn_global_load_lds(
        (const __attribute__((address_space(1))) void*)g,
        (__attribute__((address_space(3))) void*)l, 16, 0, 0);
}

__global__ __launch_bounds__(512, 1) void gemm_bf16_lse(
    const __bf16* __restrict__ xb, const __bf16* __restrict__ Wb,
    const float* __restrict__ bias, float* __restrict__ rowsum)
{
    // [buf=4][A=0/B=1][256*32 bf16] = 4 x 2 x 16 KiB = 128 KiB
    __shared__ alignas(16) __bf16 lds[4][2][BMg * BKg];

    const unsigned nblk = (MD / BMg) * (ND / BNg);   // 512
    unsigned bid  = blockIdx.x;
    unsigned sbid = (bid & 7u) * (nblk / 8u) + (bid >> 3);
    unsigned bm = sbid / (ND / BNg);
    unsigned bn = sbid % (ND / BNg);

    const unsigned tid  = threadIdx.x;
    const unsigned lane = tid & 63u;
    const unsigned wid  = tid >> 6;      // 0..7
    const unsigned wr   = wid >> 2;      // 0..1 -> 128 rows
    const unsigned wc   = wid & 3u;      // 0..3 -> 64 cols
    const unsigned lr   = lane & 15u;
    const unsigned kg   = lane >> 4;

    // staging: chunk ch -> row = ch>>2 (32-elem rows), slot = ch&3 (16B);
    // LDS linear (DMA dest = wave-uniform base + lane*16B);
    // global col-slot pre-swizzled cg = slot ^ ((row>>1)&3)  (rule #21;
    // measured 0 conflicts in round 3 with this exact involution).
    unsigned ch0 = tid, ch1 = tid + 512u;
    unsigned sr0 = ch0 >> 2, cg0 = (ch0 & 3u) ^ ((sr0 >> 1) & 3u);
    unsigned sr1 = ch1 >> 2, cg1 = (ch1 & 3u) ^ ((sr1 >> 1) & 3u);
    const __bf16* gA0 = xb + (size_t)(bm * BMg + sr0) * KD + cg0 * 8u;
    const __bf16* gA1 = xb + (size_t)(bm * BMg + sr1) * KD + cg1 * 8u;
    const __bf16* gB0 = Wb + (size_t)(bn * BNg + sr0) * KD + cg0 * 8u;
    const __bf16* gB1 = Wb + (size_t)(bn * BNg + sr1) * KD + cg1 * 8u;

    f32x4 acc[8][4] = {};

    auto stA = [&](unsigned bsel, int t) {
        gload_lds16(gA0 + (size_t)t * 32u, &lds[bsel][0][ch0 * 8u]);
        gload_lds16(gA1 + (size_t)t * 32u, &lds[bsel][0][ch1 * 8u]);
    };
    auto stB = [&](unsigned bsel, int t) {
        gload_lds16(gB0 + (size_t)t * 32u, &lds[bsel][1][ch0 * 8u]);
        gload_lds16(gB1 + (size_t)t * 32u, &lds[bsel][1][ch1 * 8u]);
    };
    // fragment reads: row stride 64B, slot kg swizzled by (row>>1)&3
    auto loadAq = [&](unsigned bsel, unsigned mh, bf16x8* dst) {
        const char* As = (const char*)&lds[bsel][0][0];
        #pragma unroll
        for (int a = 0; a < 4; ++a) {
            unsigned ro = wr * 128u + (mh * 4u + a) * 16u + lr;
            dst[a] = *(const bf16x8*)(As + ro * 64u + ((kg ^ ((ro >> 1) & 3u)) * 16u));
        }
    };
    auto loadBq = [&](unsigned bsel, bf16x8* dst) {
        const char* Bs = (const char*)&lds[bsel][1][0];
        #pragma unroll
        for (int nf = 0; nf < 4; ++nf) {
            unsigned ro = wc * 64u + nf * 16u + lr;
            dst[nf] = *(const bf16x8*)(Bs + ro * 64u + ((kg ^ ((ro >> 1) & 3u)) * 16u));
        }
    };
    auto mfma16 = [&](unsigned mh, const bf16x8* a4, const bf16x8* b4) {
        __builtin_amdgcn_s_setprio(1);
        #pragma unroll
        for (int a = 0; a < 4; ++a)
            #pragma unroll
            for (int nf = 0; nf < 4; ++nf)
                acc[mh * 4 + a][nf] = __builtin_amdgcn_mfma_f32_16x16x32_bf16(
                    a4[a], b4[nf], acc[mh * 4 + a][nf], 0, 0, 0);
        __builtin_amdgcn_s_setprio(0);
    };

    auto body = [&](int t, int vm) {
        unsigned cb = (unsigned)t & 3u;
        bf16x8 aF[4], aG[4], bF[4];
        // ---- p0 (quadrant mh=0): reads A-mh0(4) + B(4); stage A(t+3) ----
        loadAq(cb, 0, aF);
        loadBq(cb, bF);
        if (t + 3 < KTg) stA((unsigned)(t + 3) & 3u, t + 3);
        asm volatile("s_waitcnt lgkmcnt(4)" ::: "memory");   // drain hint
        __builtin_amdgcn_s_barrier();
        asm volatile("s_waitcnt lgkmcnt(0)" ::: "memory");
        __builtin_amdgcn_sched_barrier(0);                   // rule #18 fence
        mfma16(0, aF, bF);
        __builtin_amdgcn_s_barrier();
        // ---- p1 (quadrant mh=1): reads A-mh1(4); stage B(t+3);
        //      counted vmcnt certifies tile t+1 one phase before use ----
        loadAq(cb, 1, aG);
        if (t + 3 < KTg) stB((unsigned)(t + 3) & 3u, t + 3);
        if (vm == 8)      asm volatile("s_waitcnt vmcnt(8)" ::: "memory");
        else if (vm == 4) asm volatile("s_waitcnt vmcnt(4)" ::: "memory");
        else if (vm == 0) asm volatile("s_waitcnt vmcnt(0)" ::: "memory");
        __builtin_amdgcn_s_barrier();
        asm volatile("s_waitcnt lgkmcnt(0)" ::: "memory");
        __builtin_amdgcn_sched_barrier(0);
        mfma16(1, aG, bF);
        __builtin_amdgcn_s_barrier();
    };

    // prologue: stage tiles 0,1,2 (FIFO: A0 B0 A1 B1 A2 B2 = 12 loads);
    // vmcnt(8) drains exactly A(0),B(0) -> tile 0 certified.
    stA(0, 0); stB(0, 0);
    stA(1, 1); stB(1, 1);
    stA(2, 2); stB(2, 2);
    asm volatile("s_waitcnt vmcnt(8)" ::: "memory");
    __builtin_amdgcn_s_barrier();

    for (int t = 0; t < KTg; ++t) {
        int vm = (t <= KTg - 4) ? 8 : (t == KTg - 3 ? 4 : (t == KTg - 2 ? 0 : -1));
        body(t, vm);
    }

    // ---- epilogue: bias + leaky^2 + gelu^2 + exp + row partial sums ----
    // C/D layout: col = lane&15 (=lr), row = kg*4 + j
    unsigned row_base = bm * BMg + wr * 128u;
    unsigned col_base = bn * BNg + wc * 64u;
    float bb[4];
    #pragma unroll
    for (int nf = 0; nf < 4; ++nf) bb[nf] = bias[col_base + nf * 16u + lr];
    #pragma unroll
    for (int mf = 0; mf < 8; ++mf) {
        float s[4] = {0.f, 0.f, 0.f, 0.f};
        #pragma unroll
        for (int nf = 0; nf < 4; ++nf) {
            #pragma unroll
            for (int j = 0; j < 4; ++j) {
                float v = acc[mf][nf][j] + bb[nf];
                v = v > 0.0f ? v : 1e-4f * v;      // two leaky-relus fused
                v = gelu_ss(gelu_ss(v));
                s[j] += __expf(v);
            }
        }
        #pragma unroll
        for (int j = 0; j < 4; ++j) {
            float t = s[j];
            t += __shfl_xor(t, 1);
            t += __shfl_xor(t, 2);
            t += __shfl_xor(t, 4);
            t += __shfl_xor(t, 8);
            if (lr == 0)
                atomicAdd(&rowsum[row_base + mf * 16u + kg * 4u + j], t);
        }
    }
}

// ---------------------------------------------------------------------------
// Fallback (round-2 kernel): fused fp32 staging, used only if ws too small.
// ---------------------------------------------------------------------------
#define BM 256
#define BN 256
#define BK 64
#define NBLK ((MD / BM) * (ND / BN))

__device__ __forceinline__ unsigned swz(unsigned row, unsigned kbyte) {
    return row * (BK * 2u) + (kbyte ^ ((row & 7u) << 4));
}

__global__ __launch_bounds__(512, 1) void fused_gemm_lse(
    const float* __restrict__ x, const float* __restrict__ W,
    const float* __restrict__ bias, float* __restrict__ rowsum)
{
    __shared__ alignas(16) __bf16 lds[2][2][BM * BK];
    unsigned bid  = blockIdx.x;
    unsigned sbid = (bid & 7u) * (NBLK / 8u) + (bid >> 3);
    unsigned bm = sbid / (ND / BN);
    unsigned bn = sbid % (ND / BN);
    const unsigned tid  = threadIdx.x;
    const unsigned lane = tid & 63u;
    const unsigned wid  = tid >> 6;
    const unsigned wr   = wid >> 2;
    const unsigned wc   = wid & 3u;
    const unsigned lr   = lane & 15u;
    const unsigned kg   = lane >> 4;
    const float* gA = x + (size_t)bm * BM * KD;
    const float* gB = W + (size_t)bn * BN * KD;
    const unsigned s_row = tid >> 3;
    const unsigned s_c8  = tid & 7u;
    f32x4 acc[8][4] = {};
    float4 ra[8], rb[8];
    auto issue = [&](const float* g, int kt, float4* r) {
        #pragma unroll
        for (int i = 0; i < 4; ++i) {
            unsigned row = s_row + 64u * i;
            size_t goff = (size_t)row * KD + (size_t)kt * BK + (size_t)s_c8 * 8u;
            r[i * 2]     = *(const float4*)(g + goff);
            r[i * 2 + 1] = *(const float4*)(g + goff + 4);
        }
    };
    auto writeT = [&](char* dst, const float4* r) {
        #pragma unroll
        for (int i = 0; i < 4; ++i) {
            unsigned row = s_row + 64u * i;
            float4 lo = r[i * 2], hi = r[i * 2 + 1];
            bf16x8 v;
            v[0]=(__bf16)lo.x; v[1]=(__bf16)lo.y; v[2]=(__bf16)lo.z; v[3]=(__bf16)lo.w;
            v[4]=(__bf16)hi.x; v[5]=(__bf16)hi.y; v[6]=(__bf16)hi.z; v[7]=(__bf16)hi.w;
            *(bf16x8*)(dst + swz(row, s_c8 * 16u)) = v;
        }
    };
    auto compute = [&](int cur) {
        const char* AsB = (const char*)&lds[cur][0][0];
        const char* BsB = (const char*)&lds[cur][1][0];
        #pragma unroll
        for (int ks = 0; ks < 2; ++ks) {
            unsigned kb = (unsigned)ks * 64u + kg * 16u;
            bf16x8 bfr[4];
            #pragma unroll
            for (int ni = 0; ni < 4; ++ni)
                bfr[ni] = *(const bf16x8*)(BsB + swz(wc * 64u + ni * 16u + lr, kb));
            #pragma unroll
            for (int mh = 0; mh < 2; ++mh) {
                bf16x8 af[4];
                #pragma unroll
                for (int a = 0; a < 4; ++a)
                    af[a] = *(const bf16x8*)(AsB + swz(wr * 128u + mh * 64u + a * 16u + lr, kb));
                __builtin_amdgcn_s_setprio(1);
                #pragma unroll
                for (int a = 0; a < 4; ++a)
                    #pragma unroll
                    for (int ni = 0; ni < 4; ++ni)
                        acc[mh * 4 + a][ni] = __builtin_amdgcn_mfma_f32_16x16x32_bf16(
                            af[a], bfr[ni], acc[mh * 4 + a][ni], 0, 0, 0);
                __builtin_amdgcn_s_setprio(0);
            }
        }
    };
    issue(gA, 0, ra); issue(gB, 0, rb);
    writeT((char*)&lds[0][0][0], ra);
    writeT((char*)&lds[0][1][0], rb);
    __syncthreads();
    int cur = 0;
    for (int kt = 0; kt < KD / BK - 1; ++kt) {
        issue(gA, kt + 1, ra);
        issue(gB, kt + 1, rb);
        compute(cur);
        writeT((char*)&lds[cur ^ 1][0][0], ra);
        writeT((char*)&lds[cur ^ 1][1][0], rb);
        __syncthreads();
        cur ^= 1;
    }
    compute(cur);
    unsigned row_base = bm * BM + wr * 128u;
    unsigned col_base = bn * BN + wc * 64u;
    float bb[4];
    #pragma unroll
    for (int ni = 0; ni < 4; ++ni) bb[ni] = bias[col_base + ni * 16u + lr];
    #pragma unroll
    for (int mi = 0; mi < 8; ++mi) {
        float s[4] = {0.f, 0.f, 0.f, 0.f};
        #pragma unroll
        for (int ni = 0; ni < 4; ++ni) {
            #pragma unroll
            for (int j = 0; j < 4; ++j) {
                float v = acc[mi][ni][j] + bb[ni];
                v = v > 0.0f ? v : 1e-4f * v;
                v = gelu_ss(gelu_ss(v));
                s[j] += __expf(v);
            }
        }
        #pragma unroll
        for (int j = 0; j < 4; ++j) {
            float t = s[j];
            t += __shfl_xor(t, 1);
            t += __shfl_xor(t, 2);
            t += __shfl_xor(t, 4);
            t += __shfl_xor(t, 8);
            if (lr == 0)
                atomicAdd(&rowsum[row_base + mi * 16u + kg * 4u + j], t);
        }
    }
}

__global__ void lse_log(float* __restrict__ out) {
    int i = blockIdx.x * 256 + threadIdx.x;
    if (i < MD) out[i] = logf(out[i]);
}

extern "C" void kernel_launch(void* const* d_in, const int* in_sizes, int n_in,
                              void* d_out, int out_size, void* d_ws, size_t ws_size,
                              hipStream_t stream) {
    (void)in_sizes; (void)n_in; (void)out_size;
    const float* x = (const float*)d_in[0];
    const float* W = (const float*)d_in[1];
    const float* b = (const float*)d_in[2];
    float* out = (float*)d_out;

    hipMemsetAsync(out, 0, (size_t)MD * sizeof(float), stream);

    size_t need = ((size_t)MD * KD + (size_t)ND * KD) * sizeof(__bf16);  // 100.7 MB
    if (ws_size >= need) {
        __bf16* xb = (__bf16*)d_ws;
        __bf16* Wb = xb + (size_t)MD * KD;
        cvt_bf16<<<2048, 256, 0, stream>>>(x, xb, MD * KD / 8);
        cvt_bf16<<<2048, 256, 0, stream>>>(W, Wb, ND * KD / 8);
        gemm_bf16_lse<<<(MD / BMg) * (ND / BNg), 512, 0, stream>>>(xb, Wb, b, out);
    } else {
        fused_gemm_lse<<<NBLK, 512, 0, stream>>>(x, W, b, out);
    }
    lse_log<<<MD / 256, 256, 0, stream>>>(out);
}